// Round 18
// baseline (357.618 us; speedup 1.0000x reference)
//
#include <hip/hip_runtime.h>
#include <cstdint>

typedef unsigned short u16;
typedef unsigned int   u32;
typedef __attribute__((ext_vector_type(8))) short short8;
typedef __attribute__((ext_vector_type(4))) float f32x4;

constexpr int CB = 4;          // batch
constexpr int CN = 4096;       // points
constexpr int CK = 32;         // neighbors
constexpr int NPTS = CB * CN * CK;       // 524288
constexpr int NBK  = 131072;             // points per batch (N*K)
constexpr float EPSV = 1e-5f;

struct __align__(16) Q4 { u32 a, b, c, d; };

static __device__ __forceinline__ u16 f2b(float f) {
  union { float f; u32 u; } v; v.f = f;
  u32 u = v.u;
  return (u16)((u + 0x7FFFu + ((u >> 16) & 1u)) >> 16);
}
static __device__ __forceinline__ float b2f(u16 h) {
  union { u32 u; float f; } v; v.u = ((u32)h) << 16;
  return v.f;
}
static __device__ __forceinline__ u32 pk2(float lo, float hi) {
  return (u32)f2b(lo) | ((u32)f2b(hi) << 16);
}
static __device__ __forceinline__ short8 mk8(u32 a, u32 b, u32 c, u32 d) {
  union { u32 w[4]; short8 v; } u; u.w[0]=a; u.w[1]=b; u.w[2]=c; u.w[3]=d; return u.v;
}

// -------- conv1: h[b,o,n] = sum_c W[o,c] x[b,c,n]; bn1 stats --------
__global__ __launch_bounds__(256) void k_conv1(const float* __restrict__ x,
                                               const float* __restrict__ w,
                                               float* __restrict__ h,
                                               float* S, float* Q) {
  __shared__ float wl[16 * 64];
  __shared__ float ls[32];
  int tid = threadIdx.x;
  int og = blockIdx.x >> 6;            // o-group 0..3
  int cb = blockIdx.x & 63;            // column block
  for (int i = tid; i < 1024; i += 256) wl[i] = w[og * 1024 + i];
  if (tid < 32) ls[tid] = 0.f;
  __syncthreads();
  int col = cb * 256 + tid;            // (b,n)
  int b = col >> 12, n = col & 4095;
  float xr[64];
  const float* xp = x + (size_t)(b * 64) * CN + n;
  #pragma unroll
  for (int c = 0; c < 64; ++c) xr[c] = xp[(size_t)c * CN];
  int lane = tid & 63;
  for (int oo = 0; oo < 16; ++oo) {
    int o = og * 16 + oo;
    float acc = 0.f;
    const float* wr = &wl[oo * 64];
    #pragma unroll
    for (int c = 0; c < 64; ++c) acc = fmaf(wr[c], xr[c], acc);
    h[(size_t)(b * 64 + o) * CN + n] = acc;
    float v = acc, v2 = acc * acc;
    for (int d = 1; d < 64; d <<= 1) { v += __shfl_xor(v, d); v2 += __shfl_xor(v2, d); }
    if (lane == 0) { atomicAdd(&ls[oo], v); atomicAdd(&ls[16 + oo], v2); }
  }
  __syncthreads();
  if (tid < 16) atomicAdd(&S[og * 16 + tid], ls[tid]);
  else if (tid < 32) atomicAdd(&Q[og * 16 + tid - 16], ls[tid]);
}

// -------- stats -> affine --------
__global__ __launch_bounds__(64) void k_affine(const float* S, const float* Q,
                                               const float* g, const float* bt,
                                               float* A, float* Bo, int C, float inv_cnt) {
  int t = threadIdx.x;
  if (t < C) {
    float mean = S[t] * inv_cnt;
    float var = fmaxf(Q[t] * inv_cnt - mean * mean, 0.f);
    float a = g[t] * rsqrtf(var + EPSV);
    A[t] = a;
    Bo[t] = bt[t] - mean * a;
  }
}

// -------- prepM2: bf16 A-frags of M2 (kk rows, c cols) --------
__global__ __launch_bounds__(256) void k_prepM2(const float* __restrict__ M2,
                                                u16* __restrict__ m2frag) {
  int i = blockIdx.x * 256 + threadIdx.x;      // 32768 elements
  int e = i & 7, lane = (i >> 3) & 63, t = i >> 9;
  int mt = t >> 1, kc = t & 1;
  int row = 16 * mt + (lane & 15);
  int k = 32 * kc + 8 * (lane >> 4) + e;
  m2frag[i] = f2b(M2[k * 512 + row]);
}

// -------- k_y (MFMA) --------
__global__ __launch_bounds__(256) void k_y(const float* __restrict__ h,
                                           const u16* __restrict__ m2frag,
                                           const float* __restrict__ Ah,
                                           const float* __restrict__ Bh,
                                           u16* __restrict__ y16) {
  __shared__ u16 yl[4][16 * 520];
  __shared__ float abl[128];
  int tid = threadIdx.x;
  if (tid < 64) abl[tid] = Ah[tid];
  else if (tid < 128) abl[tid] = Bh[tid - 64];
  int wv = tid >> 6, lane = tid & 63, g = lane >> 4, pl = lane & 15;
  __syncthreads();
  int wid = blockIdx.x * 4 + wv;
  int n0 = wid * 16;
  int b = n0 >> 12, nloc = n0 & 4095;
  const float* sb = h + (size_t)(b * 64) * CN + nloc + pl;
  u32 w[8];
  #pragma unroll
  for (int kc = 0; kc < 2; ++kc) {
    #pragma unroll
    for (int e2 = 0; e2 < 4; ++e2) {
      int c0 = 32 * kc + 8 * g + 2 * e2;
      float v0 = fmaxf(fmaf(abl[c0],     sb[(size_t)c0 * CN],       abl[64 + c0]),     0.f);
      float v1 = fmaxf(fmaf(abl[c0 + 1], sb[(size_t)(c0 + 1) * CN], abl[64 + c0 + 1]), 0.f);
      w[kc * 4 + e2] = pk2(v0, v1);
    }
  }
  short8 Bf0 = mk8(w[0], w[1], w[2], w[3]);
  short8 Bf1 = mk8(w[4], w[5], w[6], w[7]);
  const short8* m2f = (const short8*)m2frag;
  u16* ylw = &yl[wv][0];
  #pragma unroll
  for (int mt = 0; mt < 32; ++mt) {
    short8 A0 = m2f[(mt * 2 + 0) * 64 + lane];
    short8 A1 = m2f[(mt * 2 + 1) * 64 + lane];
    f32x4 z = {0.f, 0.f, 0.f, 0.f};
    z = __builtin_amdgcn_mfma_f32_16x16x32_bf16(A0, Bf0, z, 0, 0, 0);
    z = __builtin_amdgcn_mfma_f32_16x16x32_bf16(A1, Bf1, z, 0, 0, 0);
    u32* wp = (u32*)&ylw[pl * 520 + 16 * mt + 4 * g];
    wp[0] = pk2(z[0], z[1]);
    wp[1] = pk2(z[2], z[3]);
  }
  u16* yg = y16 + (size_t)n0 * 512;
  for (int j = 0; j < 16; ++j) {
    short8 v = *(const short8*)&yl[wv][j * 520 + lane * 8];
    *(short8*)(yg + (size_t)j * 512 + lane * 8) = v;
  }
}

// -------- k_transmom: coalesced xyz read -> LDS tile -> (a) moment MFMA partials
//          (b) point-major bf16 copy xyz16t[pt][80] (ch 0..65, [66]=1.0, 67..79=0)
// R17 lesson: grid 512 = 2 blocks/CU was the binding constraint (LDS allows 4).
// Now 1024 blocks x 512 points (2 chunks); Mpart 4096 partials in its own region.
__global__ __launch_bounds__(256) void k_transmom(const float* __restrict__ xyz,
                                                  float* __restrict__ Mpart,
                                                  u16* __restrict__ xyz16t) {
  constexpr int TI[15] = {0,0,0,0,0,1,1,1,1,2,2,2,3,3,4};
  constexpr int TJ[15] = {0,1,2,3,4,1,2,3,4,2,3,4,3,4,4};
  __shared__ u16 tile[66 * 264];      // [ch][pt], stride 264 u16 = 528B (16B-aligned)
  int tid = threadIdx.x;
  int bid = blockIdx.x;               // 1024 blocks; block covers 512 points of one batch
  int wv = tid >> 6, lane = tid & 63, g = lane >> 4, pl = lane & 15;
  int b = bid >> 8;                   // 256 blocks per batch
  int rbase = (bid & 255) * 512;
  const float* xb = xyz + (size_t)b * 66 * NBK;
  f32x4 acc[15];
  #pragma unroll
  for (int t = 0; t < 15; ++t) acc[t] = (f32x4){0.f, 0.f, 0.f, 0.f};
  const short8 ones8 = mk8(0x3F803F80u, 0x3F803F80u, 0x3F803F80u, 0x3F803F80u);
  const short8 zero8 = mk8(0u, 0u, 0u, 0u);

  for (int ck = 0; ck < 2; ++ck) {
    int r = rbase + ck * 256;
    // phase A: coalesced load of 66 channel-rows x 256 pts -> bf16 tile
    for (int s = tid; s < 4224; s += 256) {
      int c = s >> 6, f4 = s & 63;
      float4 v = *(const float4*)(xb + (size_t)c * NBK + r + f4 * 4);
      u32* wp = (u32*)&tile[c * 264 + f4 * 4];
      wp[0] = pk2(v.x, v.y);
      wp[1] = pk2(v.z, v.w);
    }
    __syncthreads();
    // phase B1: moment MFMA
    #pragma unroll
    for (int grp = 0; grp < 2; ++grp) {
      int pt0 = wv * 64 + grp * 32;
      short8 fr[5];
      #pragma unroll
      for (int ci = 0; ci < 4; ++ci)
        fr[ci] = *(const short8*)&tile[(16 * ci + pl) * 264 + pt0 + 8 * g];
      if (pl < 2)       fr[4] = *(const short8*)&tile[(64 + pl) * 264 + pt0 + 8 * g];
      else if (pl == 2) fr[4] = ones8;
      else              fr[4] = zero8;
      #pragma unroll
      for (int t = 0; t < 15; ++t)
        acc[t] = __builtin_amdgcn_mfma_f32_16x16x32_bf16(fr[TI[t]], fr[TJ[t]], acc[t], 0, 0, 0);
    }
    // phase B2: transposed write, thread = point (10 x short8 = 80 channels)
    {
      int gpt = bid * 512 + ck * 256 + tid;
      u16* dst = xyz16t + (size_t)gpt * 80;
      #pragma unroll
      for (int i = 0; i < 10; ++i) {
        u32 wd[4];
        #pragma unroll
        for (int j = 0; j < 4; ++j) {
          int c0 = 8 * i + 2 * j;
          u32 lo = (c0 < 66)     ? (u32)tile[c0 * 264 + tid]       : (c0 == 66 ? 0x3F80u : 0u);
          u32 hi = (c0 + 1 < 66) ? (u32)tile[(c0 + 1) * 264 + tid] : (c0 + 1 == 66 ? 0x3F80u : 0u);
          wd[j] = lo | (hi << 16);
        }
        *(short8*)(dst + i * 8) = mk8(wd[0], wd[1], wd[2], wd[3]);
      }
    }
    __syncthreads();
  }
  int wid = bid * 4 + wv;             // [0,4096)
  float* mp = Mpart + (size_t)wid * 3840;
  #pragma unroll
  for (int t = 0; t < 15; ++t)
    *(f32x4*)(mp + t * 256 + lane * 4) = acc[t];
}

// -------- reduce partials: 4096 partials, grid (15,8), 512 each --------
__global__ __launch_bounds__(256) void k_mreduce(const float* __restrict__ Mpart,
                                                 float* __restrict__ M) {
  int e = blockIdx.x * 256 + threadIdx.x;
  int kg = blockIdx.y;
  float s = 0.f;
  for (int k = kg * 512; k < kg * 512 + 512; ++k) s += Mpart[(size_t)k * 3840 + e];
  atomicAdd(&M[e], s);
}

// -------- affine1 from moments (M as 15 tiles, layout [t][lane=g*16+pl][rr]) --------
__global__ __launch_bounds__(256) void k_affine1m(const float* __restrict__ M,
                                                  const float* __restrict__ w0,
                                                  const float* __restrict__ g0,
                                                  const float* __restrict__ b0,
                                                  float* __restrict__ A1,
                                                  float* __restrict__ B1) {
  __shared__ float lsM[67 * 68];
  __shared__ float w0l[64 * 69];
  __shared__ float red[4 * 64];
  int tid = threadIdx.x;
  const float inv = 1.f / (float)NPTS;
  for (int i = tid; i < 67 * 67; i += 256) {
    int r = i / 67, c = i % 67;
    int rr = r, cc = c;
    if ((r >> 4) > (c >> 4)) { rr = c; cc = r; }
    int ti = rr >> 4, tj = cc >> 4;
    int t = ti * (9 - ti) / 2 + tj;
    int rho = rr & 15, kap = cc & 15;
    lsM[r * 68 + c] = M[t * 256 + ((rho >> 2) * 16 + kap) * 4 + (rho & 3)] * inv;
  }
  for (int i = tid; i < 64 * 66; i += 256) {
    int o = i / 66, c = i % 66;
    w0l[o * 69 + c] = w0[i];
  }
  __syncthreads();
  int o = tid & 63, sl = tid >> 6;
  float acc2 = 0.f;
  for (int c1 = sl * 17; c1 < sl * 17 + 17; ++c1) {
    if (c1 >= 66) break;
    float inner = 0.f;
    const float* mr = &lsM[c1 * 68];
    const float* wr = &w0l[o * 69];
    for (int c2 = 0; c2 < 66; ++c2) inner = fmaf(mr[c2], wr[c2], inner);
    acc2 = fmaf(wr[c1], inner, acc2);
  }
  red[sl * 64 + o] = acc2;
  __syncthreads();
  if (sl == 0) {
    float Ez2 = red[o] + red[64 + o] + red[128 + o] + red[192 + o];
    float mean = 0.f;
    const float* wr = &w0l[o * 69];
    for (int c = 0; c < 66; ++c) mean = fmaf(wr[c], lsM[c * 68 + 66], mean);
    float var = fmaxf(Ez2 - mean * mean, 0.f);
    float a = g0[o] * rsqrtf(var + EPSV);
    A1[o] = a;
    B1[o] = b0[o] - mean * a;
  }
}

// -------- prep: bf16 A-frags for GEMM1 (affine-folded W0 + bias slot) and GEMM2 (W1) --------
__global__ __launch_bounds__(256) void k_prep(const float* __restrict__ w0,
                                              const float* __restrict__ w1,
                                              const float* __restrict__ A1,
                                              const float* __restrict__ B1,
                                              u16* __restrict__ w0frag,
                                              u16* __restrict__ w1frag) {
  int tid = threadIdx.x;
  for (int i = tid; i < 6144; i += 256) {
    int e = i & 7, lane = (i >> 3) & 63, t = i >> 9;
    int mt = t / 3, kc = t % 3;
    int row = 16 * mt + (lane & 15);
    int k = 32 * kc + 8 * (lane >> 4) + e;
    float v;
    if (k < 66)      v = A1[row] * w0[row * 66 + k];
    else if (k == 66) v = B1[row];
    else              v = 0.f;
    w0frag[i] = f2b(v);
  }
  for (int i = tid; i < 2048; i += 256) {
    int e = i & 7, lane = (i >> 3) & 63, t = i >> 9;
    int m2t = t >> 1, kc2 = t & 1;
    int row = 16 * m2t + (lane & 15);
    int k = 32 * kc2 + 8 * (lane >> 4) + e;
    w1frag[i] = f2b(w1[row * 64 + k]);
  }
}

// -------- ScoreNet fused MFMA: reads point-major xyz16t (3x16B loads/group) --------
__global__ __launch_bounds__(256) void k_s2(const u16* __restrict__ xyz16t,
                                            const u16* __restrict__ w0frag,
                                            const u16* __restrict__ w1frag,
                                            u32* __restrict__ z2p,
                                            float* S, float* Q) {
  __shared__ u16 a1l[4][16][88];
  __shared__ float ls2[64];
  int tid = threadIdx.x;
  int wv = tid >> 6, lane = tid & 63, g = lane >> 4, pl = lane & 15;
  if (tid < 64) ls2[tid] = 0.f;
  __syncthreads();

  const short8* w0f = (const short8*)w0frag;
  const short8* w1f = (const short8*)w1frag;
  short8 A0[4][3];
  #pragma unroll
  for (int mt = 0; mt < 4; ++mt)
    #pragma unroll
    for (int kc = 0; kc < 3; ++kc) A0[mt][kc] = w0f[(mt * 3 + kc) * 64 + lane];
  short8 W1f[2][2];
  #pragma unroll
  for (int m2t = 0; m2t < 2; ++m2t)
    #pragma unroll
    for (int kc2 = 0; kc2 < 2; ++kc2) W1f[m2t][kc2] = w1f[(m2t * 2 + kc2) * 64 + lane];

  float sum8[8], sq8[8];
  #pragma unroll
  for (int i = 0; i < 8; ++i) { sum8[i] = 0.f; sq8[i] = 0.f; }
  const short8 zero8 = mk8(0u, 0u, 0u, 0u);

  int wid = blockIdx.x * 4 + wv;
  for (int s = wid; s < NPTS / 32; s += 8192) {   // 2 macro-iters, 2 groups each
    int pgA = s * 16;
    int pgB = pgA + 262144;
    const u16* tpA = xyz16t + (size_t)(pgA + pl) * 80;
    const u16* tpB = xyz16t + (size_t)(pgB + pl) * 80;
    // ---- issue all loads ----
    short8 BfA0 = *(const short8*)(tpA + 8 * g);
    short8 BfA1 = *(const short8*)(tpA + 32 + 8 * g);
    short8 BfA2 = (g < 2) ? *(const short8*)(tpA + 64 + 8 * g) : zero8;
    short8 BfB0 = *(const short8*)(tpB + 8 * g);
    short8 BfB1 = *(const short8*)(tpB + 32 + 8 * g);
    short8 BfB2 = (g < 2) ? *(const short8*)(tpB + 64 + 8 * g) : zero8;
    // ---- compute group A ----
    {
      #pragma unroll
      for (int mt = 0; mt < 4; ++mt) {
        f32x4 z = {0.f, 0.f, 0.f, 0.f};
        z = __builtin_amdgcn_mfma_f32_16x16x32_bf16(A0[mt][0], BfA0, z, 0, 0, 0);
        z = __builtin_amdgcn_mfma_f32_16x16x32_bf16(A0[mt][1], BfA1, z, 0, 0, 0);
        z = __builtin_amdgcn_mfma_f32_16x16x32_bf16(A0[mt][2], BfA2, z, 0, 0, 0);
        float r0 = fmaxf(z[0], 0.f), r1 = fmaxf(z[1], 0.f);
        float r2 = fmaxf(z[2], 0.f), r3 = fmaxf(z[3], 0.f);
        u32* wp = (u32*)&a1l[wv][pl][16 * mt + 4 * g];
        wp[0] = pk2(r0, r1);
        wp[1] = pk2(r2, r3);
      }
      short8 B2f0 = *(const short8*)&a1l[wv][pl][8 * g];
      short8 B2f1 = *(const short8*)&a1l[wv][pl][32 + 8 * g];
      #pragma unroll
      for (int m2t = 0; m2t < 2; ++m2t) {
        f32x4 z2 = {0.f, 0.f, 0.f, 0.f};
        z2 = __builtin_amdgcn_mfma_f32_16x16x32_bf16(W1f[m2t][0], B2f0, z2, 0, 0, 0);
        z2 = __builtin_amdgcn_mfma_f32_16x16x32_bf16(W1f[m2t][1], B2f1, z2, 0, 0, 0);
        #pragma unroll
        for (int rr = 0; rr < 4; ++rr) {
          sum8[m2t * 4 + rr] += z2[rr];
          sq8[m2t * 4 + rr] += z2[rr] * z2[rr];
        }
        int jlo = 8 * m2t + 2 * g;
        z2p[(size_t)jlo * NPTS + pgA + pl]       = pk2(z2[0], z2[1]);
        z2p[(size_t)(jlo + 1) * NPTS + pgA + pl] = pk2(z2[2], z2[3]);
      }
    }
    // ---- compute group B ----
    {
      #pragma unroll
      for (int mt = 0; mt < 4; ++mt) {
        f32x4 z = {0.f, 0.f, 0.f, 0.f};
        z = __builtin_amdgcn_mfma_f32_16x16x32_bf16(A0[mt][0], BfB0, z, 0, 0, 0);
        z = __builtin_amdgcn_mfma_f32_16x16x32_bf16(A0[mt][1], BfB1, z, 0, 0, 0);
        z = __builtin_amdgcn_mfma_f32_16x16x32_bf16(A0[mt][2], BfB2, z, 0, 0, 0);
        float r0 = fmaxf(z[0], 0.f), r1 = fmaxf(z[1], 0.f);
        float r2 = fmaxf(z[2], 0.f), r3 = fmaxf(z[3], 0.f);
        u32* wp = (u32*)&a1l[wv][pl][16 * mt + 4 * g];
        wp[0] = pk2(r0, r1);
        wp[1] = pk2(r2, r3);
      }
      short8 B2f0 = *(const short8*)&a1l[wv][pl][8 * g];
      short8 B2f1 = *(const short8*)&a1l[wv][pl][32 + 8 * g];
      #pragma unroll
      for (int m2t = 0; m2t < 2; ++m2t) {
        f32x4 z2 = {0.f, 0.f, 0.f, 0.f};
        z2 = __builtin_amdgcn_mfma_f32_16x16x32_bf16(W1f[m2t][0], B2f0, z2, 0, 0, 0);
        z2 = __builtin_amdgcn_mfma_f32_16x16x32_bf16(W1f[m2t][1], B2f1, z2, 0, 0, 0);
        #pragma unroll
        for (int rr = 0; rr < 4; ++rr) {
          sum8[m2t * 4 + rr] += z2[rr];
          sq8[m2t * 4 + rr] += z2[rr] * z2[rr];
        }
        int jlo = 8 * m2t + 2 * g;
        z2p[(size_t)jlo * NPTS + pgB + pl]       = pk2(z2[0], z2[1]);
        z2p[(size_t)(jlo + 1) * NPTS + pgB + pl] = pk2(z2[2], z2[3]);
      }
    }
  }
  #pragma unroll
  for (int i = 0; i < 8; ++i) {
    float vS = sum8[i], vQ = sq8[i];
    for (int d = 1; d < 16; d <<= 1) { vS += __shfl_xor(vS, d); vQ += __shfl_xor(vQ, d); }
    if (pl == 0) {
      int ch = 16 * (i >> 2) + 4 * g + (i & 3);
      atomicAdd(&ls2[ch], vS);
      atomicAdd(&ls2[32 + ch], vQ);
    }
  }
  __syncthreads();
  if (tid < 32) atomicAdd(&S[tid], ls2[tid]);
  else if (tid < 64) atomicAdd(&Q[tid - 32], ls2[tid]);
}

// -------- ScoreNet pass 3 --------
__global__ __launch_bounds__(256) void k_s3(const u32* __restrict__ z2p,
                                            const float* __restrict__ w2,
                                            const float* __restrict__ A2,
                                            const float* __restrict__ B2,
                                            u32* __restrict__ z3,
                                            float* S, float* Q) {
  __shared__ float w2l[16 * 32];
  __shared__ float ab[64];
  __shared__ float ls[32];
  int tid = threadIdx.x;
  for (int i = tid; i < 512; i += 256) w2l[i] = w2[i];
  if (tid < 32) { ab[tid] = A2[tid]; ls[tid] = 0.f; }
  else if (tid < 64) ab[tid] = B2[tid - 32];
  __syncthreads();
  int p = blockIdx.x * 256 + tid;
  float a2[32];
  #pragma unroll
  for (int j = 0; j < 16; ++j) {
    u32 wj = z2p[(size_t)j * NPTS + p];
    float lo = b2f((u16)(wj & 0xFFFFu));
    float hi = b2f((u16)(wj >> 16));
    a2[2 * j]     = fmaxf(fmaf(ab[2 * j], lo, ab[32 + 2 * j]), 0.f);
    a2[2 * j + 1] = fmaxf(fmaf(ab[2 * j + 1], hi, ab[32 + 2 * j + 1]), 0.f);
  }
  int lane = tid & 63;
  float zt[16];
  for (int j = 0; j < 16; ++j) {
    float z = 0.f;
    const float* wr = &w2l[j * 32];
    #pragma unroll
    for (int c = 0; c < 32; ++c) z = fmaf(wr[c], a2[c], z);
    zt[j] = z;
    float v = z, v2 = z * z;
    for (int d = 1; d < 64; d <<= 1) { v += __shfl_xor(v, d); v2 += __shfl_xor(v2, d); }
    if (lane == 0) { atomicAdd(&ls[j], v); atomicAdd(&ls[16 + j], v2); }
  }
  u32 pkk[8];
  #pragma unroll
  for (int j = 0; j < 8; ++j) pkk[j] = pk2(zt[2 * j], zt[2 * j + 1]);
  Q4* dst = (Q4*)(z3 + (size_t)p * 8);
  #pragma unroll
  for (int i = 0; i < 2; ++i) { Q4 q; q.a = pkk[4*i]; q.b = pkk[4*i+1]; q.c = pkk[4*i+2]; q.d = pkk[4*i+3]; dst[i] = q; }
  __syncthreads();
  if (tid < 16) atomicAdd(&S[tid], ls[tid]);
  else if (tid < 32) atomicAdd(&Q[tid - 16], ls[tid]);
}

// -------- score --------
__global__ __launch_bounds__(256) void k_score(const u32* __restrict__ z3,
                                               const float* __restrict__ w3,
                                               const float* __restrict__ bias3,
                                               const float* __restrict__ A3,
                                               const float* __restrict__ B3,
                                               float* __restrict__ scores) {
  __shared__ float w3l[128];
  __shared__ float bl[8];
  __shared__ float ab[32];
  int tid = threadIdx.x;
  if (tid < 128) w3l[tid] = w3[tid];
  if (tid < 8) bl[tid] = bias3[tid];
  if (tid < 16) ab[tid] = A3[tid];
  else if (tid < 32) ab[tid] = B3[tid - 16];
  __syncthreads();
  int p = blockIdx.x * 256 + tid;
  const Q4* zp = (const Q4*)(z3 + (size_t)p * 8);
  Q4 r0 = zp[0], r1 = zp[1];
  u32 w8[8] = {r0.a, r0.b, r0.c, r0.d, r1.a, r1.b, r1.c, r1.d};
  float a3[16];
  #pragma unroll
  for (int t = 0; t < 8; ++t) {
    int c = t * 2;
    a3[c]     = fmaxf(fmaf(ab[c], b2f((u16)(w8[t] & 0xFFFFu)), ab[16 + c]), 0.f);
    a3[c + 1] = fmaxf(fmaf(ab[c + 1], b2f((u16)(w8[t] >> 16)), ab[16 + c + 1]), 0.f);
  }
  float z4[8]; float mx = -1e30f;
  #pragma unroll
  for (int mI = 0; mI < 8; ++mI) {
    float z = bl[mI];
    const float* wr = &w3l[mI * 16];
    #pragma unroll
    for (int c = 0; c < 16; ++c) z = fmaf(wr[c], a3[c], z);
    z4[mI] = z; mx = fmaxf(mx, z);
  }
  float ssum = 0.f;
  #pragma unroll
  for (int mI = 0; mI < 8; ++mI) { z4[mI] = __expf(z4[mI] - mx); ssum += z4[mI]; }
  float inv = 1.f / ssum;
  float4* sp = (float4*)(scores + (size_t)p * 8);
  sp[0] = make_float4(z4[0] * inv, z4[1] * inv, z4[2] * inv, z4[3] * inv);
  sp[1] = make_float4(z4[4] * inv, z4[5] * inv, z4[6] * inv, z4[7] * inv);
}

// -------- gather: register-staged idx + shfl broadcast -> pipelined yv loads --------
__global__ __launch_bounds__(256) void k_gather(const u16* __restrict__ y16,
                                                const float* __restrict__ scores,
                                                const int* __restrict__ idx,
                                                float* __restrict__ out0,
                                                float* S, float* Q) {
  __shared__ float ls[128];
  int tid = threadIdx.x;
  if (tid < 128) ls[tid] = 0.f;
  __syncthreads();
  int bid = blockIdx.x;                         // 2048 blocks
  int batch = (bid & 7) >> 1;                   // XCD-pair affinity per batch
  int sub = ((bid >> 3) << 1) | (bid & 1);      // [0,512)
  int wv = tid >> 6, lane = tid & 63;
  int m = lane >> 3, og = lane & 7;
  const u16* ybase = y16 + (size_t)batch * CN * 512;
  int pid0 = (batch << 12) + sub * 8 + wv * 2;  // this wave: pid0, pid0+1
  int pbase = pid0 * 32;                        // 64 consecutive p
  int jv = idx[pbase + lane];                   // coalesced: both pids' indices
  float acc0[8] = {0, 0, 0, 0, 0, 0, 0, 0};
  float acc1[8] = {0, 0, 0, 0, 0, 0, 0, 0};
  #pragma unroll 4
  for (int k = 0; k < 32; ++k) {
    int j0 = __shfl(jv, k);
    int j1 = __shfl(jv, 32 + k);
    float s0 = scores[(size_t)(pbase + k) * 8 + m];
    float s1 = scores[(size_t)(pbase + 32 + k) * 8 + m];
    short8 y0 = *(const short8*)(ybase + ((size_t)j0 << 9) + lane * 8);
    short8 y1 = *(const short8*)(ybase + ((size_t)j1 << 9) + lane * 8);
    #pragma unroll
    for (int t = 0; t < 8; ++t) {
      acc0[t] = fmaf(s0, b2f((u16)y0[t]), acc0[t]);
      acc1[t] = fmaf(s1, b2f((u16)y1[t]), acc1[t]);
    }
  }
  #pragma unroll
  for (int d = 8; d < 64; d <<= 1) {
    #pragma unroll
    for (int t = 0; t < 8; ++t) {
      acc0[t] += __shfl_xor(acc0[t], d);
      acc1[t] += __shfl_xor(acc1[t], d);
    }
  }
  if (m == 0) {
    float* op0 = out0 + (size_t)pid0 * 64 + og * 8;
    *(float4*)op0       = make_float4(acc0[0], acc0[1], acc0[2], acc0[3]);
    *(float4*)(op0 + 4) = make_float4(acc0[4], acc0[5], acc0[6], acc0[7]);
    float* op1 = out0 + (size_t)(pid0 + 1) * 64 + og * 8;
    *(float4*)op1       = make_float4(acc1[0], acc1[1], acc1[2], acc1[3]);
    *(float4*)(op1 + 4) = make_float4(acc1[4], acc1[5], acc1[6], acc1[7]);
    #pragma unroll
    for (int t = 0; t < 8; ++t) {
      float sv = acc0[t] + acc1[t];
      float qv = acc0[t] * acc0[t] + acc1[t] * acc1[t];
      atomicAdd(&ls[og * 8 + t], sv);
      atomicAdd(&ls[64 + og * 8 + t], qv);
    }
  }
  __syncthreads();
  if (tid < 64) atomicAdd(&S[tid], ls[tid]);
  else if (tid < 128) atomicAdd(&Q[tid - 64], ls[tid]);
}

// -------- bn2 + relu, transpose (b,n,o) -> (b,o,n) --------
__global__ __launch_bounds__(256) void k_bn2(const float* __restrict__ out0,
                                             const float* __restrict__ A,
                                             const float* __restrict__ Bo,
                                             float* __restrict__ outp) {
  int gid = blockIdx.x * 256 + threadIdx.x;
  for (int i = gid; i < CB * 64 * CN; i += 262144) {
    int b = i >> 18, o = (i >> 12) & 63, n = i & 4095;
    float v = out0[((size_t)((b << 12) | n)) * 64 + o];
    outp[i] = fmaxf(fmaf(A[o], v, Bo[o]), 0.f);
  }
}

extern "C" void kernel_launch(void* const* d_in, const int* in_sizes, int n_in,
                              void* d_out, int out_size, void* d_ws, size_t ws_size,
                              hipStream_t stream) {
  const float* x       = (const float*)d_in[0];
  const float* xyz     = (const float*)d_in[1];
  const float* conv1_w = (const float*)d_in[2];
  const float* bn1_g   = (const float*)d_in[3];
  const float* bn1_b   = (const float*)d_in[4];
  const float* M2      = (const float*)d_in[5];
  const float* w0      = (const float*)d_in[6];
  const float* g0      = (const float*)d_in[7];
  const float* b0      = (const float*)d_in[8];
  const float* w1      = (const float*)d_in[9];
  const float* g1      = (const float*)d_in[10];
  const float* b1      = (const float*)d_in[11];
  const float* w2      = (const float*)d_in[12];
  const float* g2      = (const float*)d_in[13];
  const float* b2      = (const float*)d_in[14];
  const float* w3      = (const float*)d_in[15];
  const float* bias3   = (const float*)d_in[16];
  const float* bn2_g   = (const float*)d_in[17];
  const float* bn2_b   = (const float*)d_in[18];
  const int*   idx     = (const int*)d_in[19];
  float* out = (float*)d_out;

  // workspace layout (bytes):
  //   h      @ 0          (4 MB)
  //   y16    @ 4194304    (16.78 MB, bf16 [B*N][512])
  //   scores @ 20971520   (16.78 MB, fp32 [NPTS][8])
  //   z2p    @ 37748736   (33.55 MB)
  //   z3     @ 71303168   (16.78 MB, bf16 [NPTS][16])
  //   out0   @ 88080384   (4 MB)
  //   sums   @ 92274688   zero 6752 f (stats 352 + M 3840) | affines | frags
  //   xyz16t @ 100663296  (83.9 MB, bf16 [NPTS][80]: ch0..65, [66]=1.0, 67..79=0)
  //   Mpart  @ 201326592  (62.9 MB, fp32 [4096][3840])
  char* wsb = (char*)d_ws;
  float* h      = (float*)wsb;
  u16*   y16    = (u16*)(wsb + 4194304);
  float* scores = (float*)(wsb + 20971520);
  u32*   z2p    = (u32*)(wsb + 37748736);
  u32*   z3     = (u32*)(wsb + 71303168);
  float* out0   = (float*)(wsb + 88080384);
  float* sums   = (float*)(wsb + 92274688);
  u16*   xyz16t = (u16*)(wsb + 100663296);
  float* Mpart  = (float*)(wsb + 201326592);
  float* S_h = sums;        float* Q_h = sums + 64;
  float* S_2 = sums + 128;  float* Q_2 = sums + 160;
  float* S_3 = sums + 192;  float* Q_3 = sums + 208;
  float* S_o = sums + 224;  float* Q_o = sums + 288;
  float* Mm  = sums + 352;                 // 15*256 = 3840 floats (tile-major)
  float* A_h = sums + 6752; float* B_h = sums + 6816;
  float* A_1 = sums + 6880; float* B_1 = sums + 6944;
  float* A_2 = sums + 7008; float* B_2 = sums + 7040;
  float* A_3 = sums + 7072; float* B_3 = sums + 7088;
  float* A_o = sums + 7104; float* B_o = sums + 7168;
  u16* w0frag = (u16*)(sums + 7232);       // 6144 u16
  u16* w1frag = w0frag + 6144;             // 2048 u16
  u16* m2frag = w1frag + 2048;             // 32768 u16 (64 KB)

  hipMemsetAsync(sums, 0, 6752 * sizeof(float), stream);

  k_prepM2<<<128, 256, 0, stream>>>(M2, m2frag);
  k_transmom<<<1024, 256, 0, stream>>>(xyz, Mpart, xyz16t);
  k_conv1<<<256, 256, 0, stream>>>(x, conv1_w, h, S_h, Q_h);
  k_affine<<<1, 64, 0, stream>>>(S_h, Q_h, bn1_g, bn1_b, A_h, B_h, 64, 1.f / 16384.f);
  k_y<<<256, 256, 0, stream>>>(h, m2frag, A_h, B_h, y16);

  k_mreduce<<<dim3(15, 8), 256, 0, stream>>>(Mpart, Mm);
  k_affine1m<<<1, 256, 0, stream>>>(Mm, w0, g0, b0, A_1, B_1);
  k_prep<<<1, 256, 0, stream>>>(w0, w1, A_1, B_1, w0frag, w1frag);
  k_s2<<<2048, 256, 0, stream>>>(xyz16t, w0frag, w1frag, z2p, S_2, Q_2);
  k_affine<<<1, 64, 0, stream>>>(S_2, Q_2, g1, b1, A_2, B_2, 32, 1.f / (float)NPTS);
  k_s3<<<2048, 256, 0, stream>>>(z2p, w2, A_2, B_2, z3, S_3, Q_3);
  k_affine<<<1, 64, 0, stream>>>(S_3, Q_3, g2, b2, A_3, B_3, 16, 1.f / (float)NPTS);

  k_score<<<2048, 256, 0, stream>>>(z3, w3, bias3, A_3, B_3, scores);
  k_gather<<<2048, 256, 0, stream>>>(y16, scores, idx, out0, S_o, Q_o);
  k_affine<<<1, 64, 0, stream>>>(S_o, Q_o, bn2_g, bn2_b, A_o, B_o, 64, 1.f / 16384.f);
  k_bn2<<<1024, 256, 0, stream>>>(out0, A_o, B_o, out);
}

// Round 19
// 310.145 us; speedup vs baseline: 1.1531x; 1.1531x over previous
//
#include <hip/hip_runtime.h>
#include <cstdint>

typedef unsigned short u16;
typedef unsigned int   u32;
typedef __attribute__((ext_vector_type(8))) short short8;
typedef __attribute__((ext_vector_type(4))) float f32x4;

constexpr int CB = 4;          // batch
constexpr int CN = 4096;       // points
constexpr int CK = 32;         // neighbors
constexpr int NPTS = CB * CN * CK;       // 524288
constexpr int NBK  = 131072;             // points per batch (N*K)
constexpr float EPSV = 1e-5f;

struct __align__(16) Q4 { u32 a, b, c, d; };

static __device__ __forceinline__ u16 f2b(float f) {
  union { float f; u32 u; } v; v.f = f;
  u32 u = v.u;
  return (u16)((u + 0x7FFFu + ((u >> 16) & 1u)) >> 16);
}
static __device__ __forceinline__ float b2f(u16 h) {
  union { u32 u; float f; } v; v.u = ((u32)h) << 16;
  return v.f;
}
static __device__ __forceinline__ u32 pk2(float lo, float hi) {
  return (u32)f2b(lo) | ((u32)f2b(hi) << 16);
}
static __device__ __forceinline__ short8 mk8(u32 a, u32 b, u32 c, u32 d) {
  union { u32 w[4]; short8 v; } u; u.w[0]=a; u.w[1]=b; u.w[2]=c; u.w[3]=d; return u.v;
}

// -------- conv1: h[b,o,n] = sum_c W[o,c] x[b,c,n]; bn1 stats --------
__global__ __launch_bounds__(256) void k_conv1(const float* __restrict__ x,
                                               const float* __restrict__ w,
                                               float* __restrict__ h,
                                               float* S, float* Q) {
  __shared__ float wl[16 * 64];
  __shared__ float ls[32];
  int tid = threadIdx.x;
  int og = blockIdx.x >> 6;            // o-group 0..3
  int cb = blockIdx.x & 63;            // column block
  for (int i = tid; i < 1024; i += 256) wl[i] = w[og * 1024 + i];
  if (tid < 32) ls[tid] = 0.f;
  __syncthreads();
  int col = cb * 256 + tid;            // (b,n)
  int b = col >> 12, n = col & 4095;
  float xr[64];
  const float* xp = x + (size_t)(b * 64) * CN + n;
  #pragma unroll
  for (int c = 0; c < 64; ++c) xr[c] = xp[(size_t)c * CN];
  int lane = tid & 63;
  for (int oo = 0; oo < 16; ++oo) {
    int o = og * 16 + oo;
    float acc = 0.f;
    const float* wr = &wl[oo * 64];
    #pragma unroll
    for (int c = 0; c < 64; ++c) acc = fmaf(wr[c], xr[c], acc);
    h[(size_t)(b * 64 + o) * CN + n] = acc;
    float v = acc, v2 = acc * acc;
    for (int d = 1; d < 64; d <<= 1) { v += __shfl_xor(v, d); v2 += __shfl_xor(v2, d); }
    if (lane == 0) { atomicAdd(&ls[oo], v); atomicAdd(&ls[16 + oo], v2); }
  }
  __syncthreads();
  if (tid < 16) atomicAdd(&S[og * 16 + tid], ls[tid]);
  else if (tid < 32) atomicAdd(&Q[og * 16 + tid - 16], ls[tid]);
}

// -------- stats -> affine --------
__global__ __launch_bounds__(64) void k_affine(const float* S, const float* Q,
                                               const float* g, const float* bt,
                                               float* A, float* Bo, int C, float inv_cnt) {
  int t = threadIdx.x;
  if (t < C) {
    float mean = S[t] * inv_cnt;
    float var = fmaxf(Q[t] * inv_cnt - mean * mean, 0.f);
    float a = g[t] * rsqrtf(var + EPSV);
    A[t] = a;
    Bo[t] = bt[t] - mean * a;
  }
}

// -------- prepM2: bf16 A-frags of M2 (kk rows, c cols) --------
__global__ __launch_bounds__(256) void k_prepM2(const float* __restrict__ M2,
                                                u16* __restrict__ m2frag) {
  int i = blockIdx.x * 256 + threadIdx.x;      // 32768 elements
  int e = i & 7, lane = (i >> 3) & 63, t = i >> 9;
  int mt = t >> 1, kc = t & 1;
  int row = 16 * mt + (lane & 15);
  int k = 32 * kc + 8 * (lane >> 4) + e;
  m2frag[i] = f2b(M2[k * 512 + row]);
}

// -------- k_y (MFMA) --------
__global__ __launch_bounds__(256) void k_y(const float* __restrict__ h,
                                           const u16* __restrict__ m2frag,
                                           const float* __restrict__ Ah,
                                           const float* __restrict__ Bh,
                                           u16* __restrict__ y16) {
  __shared__ u16 yl[4][16 * 520];
  __shared__ float abl[128];
  int tid = threadIdx.x;
  if (tid < 64) abl[tid] = Ah[tid];
  else if (tid < 128) abl[tid] = Bh[tid - 64];
  int wv = tid >> 6, lane = tid & 63, g = lane >> 4, pl = lane & 15;
  __syncthreads();
  int wid = blockIdx.x * 4 + wv;
  int n0 = wid * 16;
  int b = n0 >> 12, nloc = n0 & 4095;
  const float* sb = h + (size_t)(b * 64) * CN + nloc + pl;
  u32 w[8];
  #pragma unroll
  for (int kc = 0; kc < 2; ++kc) {
    #pragma unroll
    for (int e2 = 0; e2 < 4; ++e2) {
      int c0 = 32 * kc + 8 * g + 2 * e2;
      float v0 = fmaxf(fmaf(abl[c0],     sb[(size_t)c0 * CN],       abl[64 + c0]),     0.f);
      float v1 = fmaxf(fmaf(abl[c0 + 1], sb[(size_t)(c0 + 1) * CN], abl[64 + c0 + 1]), 0.f);
      w[kc * 4 + e2] = pk2(v0, v1);
    }
  }
  short8 Bf0 = mk8(w[0], w[1], w[2], w[3]);
  short8 Bf1 = mk8(w[4], w[5], w[6], w[7]);
  const short8* m2f = (const short8*)m2frag;
  u16* ylw = &yl[wv][0];
  #pragma unroll
  for (int mt = 0; mt < 32; ++mt) {
    short8 A0 = m2f[(mt * 2 + 0) * 64 + lane];
    short8 A1 = m2f[(mt * 2 + 1) * 64 + lane];
    f32x4 z = {0.f, 0.f, 0.f, 0.f};
    z = __builtin_amdgcn_mfma_f32_16x16x32_bf16(A0, Bf0, z, 0, 0, 0);
    z = __builtin_amdgcn_mfma_f32_16x16x32_bf16(A1, Bf1, z, 0, 0, 0);
    u32* wp = (u32*)&ylw[pl * 520 + 16 * mt + 4 * g];
    wp[0] = pk2(z[0], z[1]);
    wp[1] = pk2(z[2], z[3]);
  }
  u16* yg = y16 + (size_t)n0 * 512;
  for (int j = 0; j < 16; ++j) {
    short8 v = *(const short8*)&yl[wv][j * 520 + lane * 8];
    *(short8*)(yg + (size_t)j * 512 + lane * 8) = v;
  }
}

// -------- load 5 bf16 fragments (66 channels + ones + pad) for one 32-point group --------
static __device__ __forceinline__ void ld_frags(const float* __restrict__ xyz,
                                                int c, int g, int pl, short8 fr[5]) {
  int pbase = c * 32;
  int b = pbase >> 17, r = pbase & (NBK - 1);
  const float* base = xyz + (size_t)b * 66 * NBK + r + g * 8;
  #pragma unroll
  for (int ci = 0; ci < 4; ++ci) {
    const float* p = base + (size_t)(16 * ci + pl) * NBK;
    float4 v0 = *(const float4*)p;
    float4 v1 = *(const float4*)(p + 4);
    fr[ci] = mk8(pk2(v0.x, v0.y), pk2(v0.z, v0.w), pk2(v1.x, v1.y), pk2(v1.z, v1.w));
  }
  if (pl < 2) {
    const float* p = base + (size_t)(64 + pl) * NBK;
    float4 v0 = *(const float4*)p;
    float4 v1 = *(const float4*)(p + 4);
    fr[4] = mk8(pk2(v0.x, v0.y), pk2(v0.z, v0.w), pk2(v1.x, v1.y), pk2(v1.z, v1.w));
  } else if (pl == 2) {
    fr[4] = mk8(0x3F803F80u, 0x3F803F80u, 0x3F803F80u, 0x3F803F80u);
  } else {
    fr[4] = mk8(0u, 0u, 0u, 0u);
  }
}

// -------- moment kernel: per-WAVE partial of the 15-tile upper triangle --------
__global__ __launch_bounds__(256) void k_moment(const float* __restrict__ xyz,
                                                float* __restrict__ Mpart) {
  constexpr int TI[15] = {0,0,0,0,0,1,1,1,1,2,2,2,3,3,4};
  constexpr int TJ[15] = {0,1,2,3,4,1,2,3,4,2,3,4,3,4,4};
  int tid = threadIdx.x;
  int wv = tid >> 6;
  int wid = blockIdx.x * 4 + wv;              // 512 blocks -> wid in [0,2048)
  int lane = tid & 63, g = lane >> 4, pl = lane & 15;
  f32x4 acc[15];
  #pragma unroll
  for (int t = 0; t < 15; ++t) acc[t] = (f32x4){0.f, 0.f, 0.f, 0.f};
  for (int cc = wid; cc < NPTS / 32; cc += 4096) {
    short8 fr0[5], fr1[5];
    ld_frags(xyz, cc,        g, pl, fr0);
    ld_frags(xyz, cc + 2048, g, pl, fr1);
    #pragma unroll
    for (int t = 0; t < 15; ++t)
      acc[t] = __builtin_amdgcn_mfma_f32_16x16x32_bf16(fr0[TI[t]], fr0[TJ[t]], acc[t], 0, 0, 0);
    #pragma unroll
    for (int t = 0; t < 15; ++t)
      acc[t] = __builtin_amdgcn_mfma_f32_16x16x32_bf16(fr1[TI[t]], fr1[TJ[t]], acc[t], 0, 0, 0);
  }
  float* mp = Mpart + (size_t)wid * 3840;
  #pragma unroll
  for (int t = 0; t < 15; ++t)
    *(f32x4*)(mp + t * 256 + lane * 4) = acc[t];
}

// -------- reduce partials --------
__global__ __launch_bounds__(256) void k_mreduce(const float* __restrict__ Mpart,
                                                 float* __restrict__ M) {
  int e = blockIdx.x * 256 + threadIdx.x;
  int kg = blockIdx.y;
  float s = 0.f;
  for (int k = kg * 256; k < kg * 256 + 256; ++k) s += Mpart[(size_t)k * 3840 + e];
  atomicAdd(&M[e], s);
}

// -------- affine1 from moments (M as 15 tiles, layout [t][lane=g*16+pl][rr]) --------
__global__ __launch_bounds__(256) void k_affine1m(const float* __restrict__ M,
                                                  const float* __restrict__ w0,
                                                  const float* __restrict__ g0,
                                                  const float* __restrict__ b0,
                                                  float* __restrict__ A1,
                                                  float* __restrict__ B1) {
  __shared__ float lsM[67 * 68];
  __shared__ float w0l[64 * 69];
  __shared__ float red[4 * 64];
  int tid = threadIdx.x;
  const float inv = 1.f / (float)NPTS;
  for (int i = tid; i < 67 * 67; i += 256) {
    int r = i / 67, c = i % 67;
    int rr = r, cc = c;
    if ((r >> 4) > (c >> 4)) { rr = c; cc = r; }
    int ti = rr >> 4, tj = cc >> 4;
    int t = ti * (9 - ti) / 2 + tj;
    int rho = rr & 15, kap = cc & 15;
    lsM[r * 68 + c] = M[t * 256 + ((rho >> 2) * 16 + kap) * 4 + (rho & 3)] * inv;
  }
  for (int i = tid; i < 64 * 66; i += 256) {
    int o = i / 66, c = i % 66;
    w0l[o * 69 + c] = w0[i];
  }
  __syncthreads();
  int o = tid & 63, sl = tid >> 6;
  float acc2 = 0.f;
  for (int c1 = sl * 17; c1 < sl * 17 + 17; ++c1) {
    if (c1 >= 66) break;
    float inner = 0.f;
    const float* mr = &lsM[c1 * 68];
    const float* wr = &w0l[o * 69];
    for (int c2 = 0; c2 < 66; ++c2) inner = fmaf(mr[c2], wr[c2], inner);
    acc2 = fmaf(wr[c1], inner, acc2);
  }
  red[sl * 64 + o] = acc2;
  __syncthreads();
  if (sl == 0) {
    float Ez2 = red[o] + red[64 + o] + red[128 + o] + red[192 + o];
    float mean = 0.f;
    const float* wr = &w0l[o * 69];
    for (int c = 0; c < 66; ++c) mean = fmaf(wr[c], lsM[c * 68 + 66], mean);
    float var = fmaxf(Ez2 - mean * mean, 0.f);
    float a = g0[o] * rsqrtf(var + EPSV);
    A1[o] = a;
    B1[o] = b0[o] - mean * a;
  }
}

// -------- prep: bf16 A-frags for GEMM1 (affine-folded W0 + bias slot) and GEMM2 (W1) --------
__global__ __launch_bounds__(256) void k_prep(const float* __restrict__ w0,
                                              const float* __restrict__ w1,
                                              const float* __restrict__ A1,
                                              const float* __restrict__ B1,
                                              u16* __restrict__ w0frag,
                                              u16* __restrict__ w1frag) {
  int tid = threadIdx.x;
  for (int i = tid; i < 6144; i += 256) {
    int e = i & 7, lane = (i >> 3) & 63, t = i >> 9;
    int mt = t / 3, kc = t % 3;
    int row = 16 * mt + (lane & 15);
    int k = 32 * kc + 8 * (lane >> 4) + e;
    float v;
    if (k < 66)      v = A1[row] * w0[row * 66 + k];
    else if (k == 66) v = B1[row];
    else              v = 0.f;
    w0frag[i] = f2b(v);
  }
  for (int i = tid; i < 2048; i += 256) {
    int e = i & 7, lane = (i >> 3) & 63, t = i >> 9;
    int m2t = t >> 1, kc2 = t & 1;
    int row = 16 * m2t + (lane & 15);
    int k = 32 * kc2 + 8 * (lane >> 4) + e;
    w1frag[i] = f2b(w1[row * 64 + k]);
  }
}

// -------- ScoreNet fused MFMA: a1 = relu(W0^.s + bias), z2^T = W1.a1; stats2; z2 planes --------
__global__ __launch_bounds__(256) void k_s2(const float* __restrict__ xyz,
                                            const u16* __restrict__ w0frag,
                                            const u16* __restrict__ w1frag,
                                            u32* __restrict__ z2p,
                                            float* S, float* Q) {
  __shared__ u16 a1l[4][16][88];
  __shared__ float ls2[64];
  int tid = threadIdx.x;
  int wv = tid >> 6, lane = tid & 63, g = lane >> 4, pl = lane & 15;
  if (tid < 64) ls2[tid] = 0.f;
  __syncthreads();

  const short8* w0f = (const short8*)w0frag;
  const short8* w1f = (const short8*)w1frag;
  short8 A0[4][3];
  #pragma unroll
  for (int mt = 0; mt < 4; ++mt)
    #pragma unroll
    for (int kc = 0; kc < 3; ++kc) A0[mt][kc] = w0f[(mt * 3 + kc) * 64 + lane];
  short8 W1f[2][2];
  #pragma unroll
  for (int m2t = 0; m2t < 2; ++m2t)
    #pragma unroll
    for (int kc2 = 0; kc2 < 2; ++kc2) W1f[m2t][kc2] = w1f[(m2t * 2 + kc2) * 64 + lane];

  float sum8[8], sq8[8];
  #pragma unroll
  for (int i = 0; i < 8; ++i) { sum8[i] = 0.f; sq8[i] = 0.f; }

  int wid = blockIdx.x * 4 + wv;
  for (int s = wid; s < NPTS / 32; s += 8192) {   // 2 macro-iters, 2 groups each
    int pgA = s * 16;
    int pgB = pgA + 262144;                       // s + 16384 groups
    int bA = pgA >> 17, rA = pgA & (NBK - 1);
    int bB = pgB >> 17, rB = pgB & (NBK - 1);
    const float* sbA = xyz + (size_t)bA * 66 * NBK + rA + pl;
    const float* sbB = xyz + (size_t)bB * 66 * NBK + rB + pl;
    // ---- issue ALL loads (36 outstanding) ----
    float vA[16], vB[16];
    #pragma unroll
    for (int e = 0; e < 8; ++e) vA[e]     = sbA[(size_t)(8 * g + e) * NBK];
    #pragma unroll
    for (int e = 0; e < 8; ++e) vA[8 + e] = sbA[(size_t)(32 + 8 * g + e) * NBK];
    #pragma unroll
    for (int e = 0; e < 8; ++e) vB[e]     = sbB[(size_t)(8 * g + e) * NBK];
    #pragma unroll
    for (int e = 0; e < 8; ++e) vB[8 + e] = sbB[(size_t)(32 + 8 * g + e) * NBK];
    float v64A = 0.f, v65A = 0.f, v64B = 0.f, v65B = 0.f;
    if (g == 0) {
      v64A = sbA[(size_t)64 * NBK]; v65A = sbA[(size_t)65 * NBK];
      v64B = sbB[(size_t)64 * NBK]; v65B = sbB[(size_t)65 * NBK];
    }
    // ---- compute group A ----
    {
      u32 c2a = 0u, c2b = 0u;
      if (g == 0) { c2a = pk2(v64A, v65A); c2b = 0x00003F80u; }
      short8 Bf0 = mk8(pk2(vA[0], vA[1]), pk2(vA[2], vA[3]), pk2(vA[4], vA[5]), pk2(vA[6], vA[7]));
      short8 Bf1 = mk8(pk2(vA[8], vA[9]), pk2(vA[10], vA[11]), pk2(vA[12], vA[13]), pk2(vA[14], vA[15]));
      short8 Bf2 = mk8(c2a, c2b, 0u, 0u);
      #pragma unroll
      for (int mt = 0; mt < 4; ++mt) {
        f32x4 z = {0.f, 0.f, 0.f, 0.f};
        z = __builtin_amdgcn_mfma_f32_16x16x32_bf16(A0[mt][0], Bf0, z, 0, 0, 0);
        z = __builtin_amdgcn_mfma_f32_16x16x32_bf16(A0[mt][1], Bf1, z, 0, 0, 0);
        z = __builtin_amdgcn_mfma_f32_16x16x32_bf16(A0[mt][2], Bf2, z, 0, 0, 0);
        float r0 = fmaxf(z[0], 0.f), r1 = fmaxf(z[1], 0.f);
        float r2 = fmaxf(z[2], 0.f), r3 = fmaxf(z[3], 0.f);
        u32* wp = (u32*)&a1l[wv][pl][16 * mt + 4 * g];
        wp[0] = pk2(r0, r1);
        wp[1] = pk2(r2, r3);
      }
      short8 B2f0 = *(const short8*)&a1l[wv][pl][8 * g];
      short8 B2f1 = *(const short8*)&a1l[wv][pl][32 + 8 * g];
      #pragma unroll
      for (int m2t = 0; m2t < 2; ++m2t) {
        f32x4 z2 = {0.f, 0.f, 0.f, 0.f};
        z2 = __builtin_amdgcn_mfma_f32_16x16x32_bf16(W1f[m2t][0], B2f0, z2, 0, 0, 0);
        z2 = __builtin_amdgcn_mfma_f32_16x16x32_bf16(W1f[m2t][1], B2f1, z2, 0, 0, 0);
        #pragma unroll
        for (int rr = 0; rr < 4; ++rr) {
          sum8[m2t * 4 + rr] += z2[rr];
          sq8[m2t * 4 + rr] += z2[rr] * z2[rr];
        }
        int jlo = 8 * m2t + 2 * g;
        z2p[(size_t)jlo * NPTS + pgA + pl]       = pk2(z2[0], z2[1]);
        z2p[(size_t)(jlo + 1) * NPTS + pgA + pl] = pk2(z2[2], z2[3]);
      }
    }
    // ---- compute group B ----
    {
      u32 c2a = 0u, c2b = 0u;
      if (g == 0) { c2a = pk2(v64B, v65B); c2b = 0x00003F80u; }
      short8 Bf0 = mk8(pk2(vB[0], vB[1]), pk2(vB[2], vB[3]), pk2(vB[4], vB[5]), pk2(vB[6], vB[7]));
      short8 Bf1 = mk8(pk2(vB[8], vB[9]), pk2(vB[10], vB[11]), pk2(vB[12], vB[13]), pk2(vB[14], vB[15]));
      short8 Bf2 = mk8(c2a, c2b, 0u, 0u);
      #pragma unroll
      for (int mt = 0; mt < 4; ++mt) {
        f32x4 z = {0.f, 0.f, 0.f, 0.f};
        z = __builtin_amdgcn_mfma_f32_16x16x32_bf16(A0[mt][0], Bf0, z, 0, 0, 0);
        z = __builtin_amdgcn_mfma_f32_16x16x32_bf16(A0[mt][1], Bf1, z, 0, 0, 0);
        z = __builtin_amdgcn_mfma_f32_16x16x32_bf16(A0[mt][2], Bf2, z, 0, 0, 0);
        float r0 = fmaxf(z[0], 0.f), r1 = fmaxf(z[1], 0.f);
        float r2 = fmaxf(z[2], 0.f), r3 = fmaxf(z[3], 0.f);
        u32* wp = (u32*)&a1l[wv][pl][16 * mt + 4 * g];
        wp[0] = pk2(r0, r1);
        wp[1] = pk2(r2, r3);
      }
      short8 B2f0 = *(const short8*)&a1l[wv][pl][8 * g];
      short8 B2f1 = *(const short8*)&a1l[wv][pl][32 + 8 * g];
      #pragma unroll
      for (int m2t = 0; m2t < 2; ++m2t) {
        f32x4 z2 = {0.f, 0.f, 0.f, 0.f};
        z2 = __builtin_amdgcn_mfma_f32_16x16x32_bf16(W1f[m2t][0], B2f0, z2, 0, 0, 0);
        z2 = __builtin_amdgcn_mfma_f32_16x16x32_bf16(W1f[m2t][1], B2f1, z2, 0, 0, 0);
        #pragma unroll
        for (int rr = 0; rr < 4; ++rr) {
          sum8[m2t * 4 + rr] += z2[rr];
          sq8[m2t * 4 + rr] += z2[rr] * z2[rr];
        }
        int jlo = 8 * m2t + 2 * g;
        z2p[(size_t)jlo * NPTS + pgB + pl]       = pk2(z2[0], z2[1]);
        z2p[(size_t)(jlo + 1) * NPTS + pgB + pl] = pk2(z2[2], z2[3]);
      }
    }
  }
  #pragma unroll
  for (int i = 0; i < 8; ++i) {
    float vS = sum8[i], vQ = sq8[i];
    for (int d = 1; d < 16; d <<= 1) { vS += __shfl_xor(vS, d); vQ += __shfl_xor(vQ, d); }
    if (pl == 0) {
      int ch = 16 * (i >> 2) + 4 * g + (i & 3);
      atomicAdd(&ls2[ch], vS);
      atomicAdd(&ls2[32 + ch], vQ);
    }
  }
  __syncthreads();
  if (tid < 32) atomicAdd(&S[tid], ls2[tid]);
  else if (tid < 64) atomicAdd(&Q[tid - 32], ls2[tid]);
}

// -------- ScoreNet pass 3 --------
__global__ __launch_bounds__(256) void k_s3(const u32* __restrict__ z2p,
                                            const float* __restrict__ w2,
                                            const float* __restrict__ A2,
                                            const float* __restrict__ B2,
                                            u32* __restrict__ z3,
                                            float* S, float* Q) {
  __shared__ float w2l[16 * 32];
  __shared__ float ab[64];
  __shared__ float ls[32];
  int tid = threadIdx.x;
  for (int i = tid; i < 512; i += 256) w2l[i] = w2[i];
  if (tid < 32) { ab[tid] = A2[tid]; ls[tid] = 0.f; }
  else if (tid < 64) ab[tid] = B2[tid - 32];
  __syncthreads();
  int p = blockIdx.x * 256 + tid;
  float a2[32];
  #pragma unroll
  for (int j = 0; j < 16; ++j) {
    u32 wj = z2p[(size_t)j * NPTS + p];
    float lo = b2f((u16)(wj & 0xFFFFu));
    float hi = b2f((u16)(wj >> 16));
    a2[2 * j]     = fmaxf(fmaf(ab[2 * j], lo, ab[32 + 2 * j]), 0.f);
    a2[2 * j + 1] = fmaxf(fmaf(ab[2 * j + 1], hi, ab[32 + 2 * j + 1]), 0.f);
  }
  int lane = tid & 63;
  float zt[16];
  for (int j = 0; j < 16; ++j) {
    float z = 0.f;
    const float* wr = &w2l[j * 32];
    #pragma unroll
    for (int c = 0; c < 32; ++c) z = fmaf(wr[c], a2[c], z);
    zt[j] = z;
    float v = z, v2 = z * z;
    for (int d = 1; d < 64; d <<= 1) { v += __shfl_xor(v, d); v2 += __shfl_xor(v2, d); }
    if (lane == 0) { atomicAdd(&ls[j], v); atomicAdd(&ls[16 + j], v2); }
  }
  u32 pkk[8];
  #pragma unroll
  for (int j = 0; j < 8; ++j) pkk[j] = pk2(zt[2 * j], zt[2 * j + 1]);
  Q4* dst = (Q4*)(z3 + (size_t)p * 8);
  #pragma unroll
  for (int i = 0; i < 2; ++i) { Q4 q; q.a = pkk[4*i]; q.b = pkk[4*i+1]; q.c = pkk[4*i+2]; q.d = pkk[4*i+3]; dst[i] = q; }
  __syncthreads();
  if (tid < 16) atomicAdd(&S[tid], ls[tid]);
  else if (tid < 32) atomicAdd(&Q[tid - 16], ls[tid]);
}

// -------- score --------
__global__ __launch_bounds__(256) void k_score(const u32* __restrict__ z3,
                                               const float* __restrict__ w3,
                                               const float* __restrict__ bias3,
                                               const float* __restrict__ A3,
                                               const float* __restrict__ B3,
                                               float* __restrict__ scores) {
  __shared__ float w3l[128];
  __shared__ float bl[8];
  __shared__ float ab[32];
  int tid = threadIdx.x;
  if (tid < 128) w3l[tid] = w3[tid];
  if (tid < 8) bl[tid] = bias3[tid];
  if (tid < 16) ab[tid] = A3[tid];
  else if (tid < 32) ab[tid] = B3[tid - 16];
  __syncthreads();
  int p = blockIdx.x * 256 + tid;
  const Q4* zp = (const Q4*)(z3 + (size_t)p * 8);
  Q4 r0 = zp[0], r1 = zp[1];
  u32 w8[8] = {r0.a, r0.b, r0.c, r0.d, r1.a, r1.b, r1.c, r1.d};
  float a3[16];
  #pragma unroll
  for (int t = 0; t < 8; ++t) {
    int c = t * 2;
    a3[c]     = fmaxf(fmaf(ab[c], b2f((u16)(w8[t] & 0xFFFFu)), ab[16 + c]), 0.f);
    a3[c + 1] = fmaxf(fmaf(ab[c + 1], b2f((u16)(w8[t] >> 16)), ab[16 + c + 1]), 0.f);
  }
  float z4[8]; float mx = -1e30f;
  #pragma unroll
  for (int mI = 0; mI < 8; ++mI) {
    float z = bl[mI];
    const float* wr = &w3l[mI * 16];
    #pragma unroll
    for (int c = 0; c < 16; ++c) z = fmaf(wr[c], a3[c], z);
    z4[mI] = z; mx = fmaxf(mx, z);
  }
  float ssum = 0.f;
  #pragma unroll
  for (int mI = 0; mI < 8; ++mI) { z4[mI] = __expf(z4[mI] - mx); ssum += z4[mI]; }
  float inv = 1.f / ssum;
  float4* sp = (float4*)(scores + (size_t)p * 8);
  sp[0] = make_float4(z4[0] * inv, z4[1] * inv, z4[2] * inv, z4[3] * inv);
  sp[1] = make_float4(z4[4] * inv, z4[5] * inv, z4[6] * inv, z4[7] * inv);
}

// -------- gather: register-staged idx + shfl broadcast -> pipelined yv loads --------
__global__ __launch_bounds__(256) void k_gather(const u16* __restrict__ y16,
                                                const float* __restrict__ scores,
                                                const int* __restrict__ idx,
                                                float* __restrict__ out0,
                                                float* S, float* Q) {
  __shared__ float ls[128];
  int tid = threadIdx.x;
  if (tid < 128) ls[tid] = 0.f;
  __syncthreads();
  int bid = blockIdx.x;                         // 2048 blocks
  int batch = (bid & 7) >> 1;                   // XCD-pair affinity per batch
  int sub = ((bid >> 3) << 1) | (bid & 1);      // [0,512)
  int wv = tid >> 6, lane = tid & 63;
  int m = lane >> 3, og = lane & 7;
  const u16* ybase = y16 + (size_t)batch * CN * 512;
  int pid0 = (batch << 12) + sub * 8 + wv * 2;  // this wave: pid0, pid0+1
  int pbase = pid0 * 32;                        // 64 consecutive p
  int jv = idx[pbase + lane];                   // coalesced: both pids' indices
  float acc0[8] = {0, 0, 0, 0, 0, 0, 0, 0};
  float acc1[8] = {0, 0, 0, 0, 0, 0, 0, 0};
  #pragma unroll 4
  for (int k = 0; k < 32; ++k) {
    int j0 = __shfl(jv, k);
    int j1 = __shfl(jv, 32 + k);
    float s0 = scores[(size_t)(pbase + k) * 8 + m];
    float s1 = scores[(size_t)(pbase + 32 + k) * 8 + m];
    short8 y0 = *(const short8*)(ybase + ((size_t)j0 << 9) + lane * 8);
    short8 y1 = *(const short8*)(ybase + ((size_t)j1 << 9) + lane * 8);
    #pragma unroll
    for (int t = 0; t < 8; ++t) {
      acc0[t] = fmaf(s0, b2f((u16)y0[t]), acc0[t]);
      acc1[t] = fmaf(s1, b2f((u16)y1[t]), acc1[t]);
    }
  }
  #pragma unroll
  for (int d = 8; d < 64; d <<= 1) {
    #pragma unroll
    for (int t = 0; t < 8; ++t) {
      acc0[t] += __shfl_xor(acc0[t], d);
      acc1[t] += __shfl_xor(acc1[t], d);
    }
  }
  if (m == 0) {
    float* op0 = out0 + (size_t)pid0 * 64 + og * 8;
    *(float4*)op0       = make_float4(acc0[0], acc0[1], acc0[2], acc0[3]);
    *(float4*)(op0 + 4) = make_float4(acc0[4], acc0[5], acc0[6], acc0[7]);
    float* op1 = out0 + (size_t)(pid0 + 1) * 64 + og * 8;
    *(float4*)op1       = make_float4(acc1[0], acc1[1], acc1[2], acc1[3]);
    *(float4*)(op1 + 4) = make_float4(acc1[4], acc1[5], acc1[6], acc1[7]);
    #pragma unroll
    for (int t = 0; t < 8; ++t) {
      float sv = acc0[t] + acc1[t];
      float qv = acc0[t] * acc0[t] + acc1[t] * acc1[t];
      atomicAdd(&ls[og * 8 + t], sv);
      atomicAdd(&ls[64 + og * 8 + t], qv);
    }
  }
  __syncthreads();
  if (tid < 64) atomicAdd(&S[tid], ls[tid]);
  else if (tid < 128) atomicAdd(&Q[tid - 64], ls[tid]);
}

// -------- bn2 + relu, transpose (b,n,o) -> (b,o,n) --------
__global__ __launch_bounds__(256) void k_bn2(const float* __restrict__ out0,
                                             const float* __restrict__ A,
                                             const float* __restrict__ Bo,
                                             float* __restrict__ outp) {
  int gid = blockIdx.x * 256 + threadIdx.x;
  for (int i = gid; i < CB * 64 * CN; i += 262144) {
    int b = i >> 18, o = (i >> 12) & 63, n = i & 4095;
    float v = out0[((size_t)((b << 12) | n)) * 64 + o];
    outp[i] = fmaxf(fmaf(A[o], v, Bo[o]), 0.f);
  }
}

extern "C" void kernel_launch(void* const* d_in, const int* in_sizes, int n_in,
                              void* d_out, int out_size, void* d_ws, size_t ws_size,
                              hipStream_t stream) {
  const float* x       = (const float*)d_in[0];
  const float* xyz     = (const float*)d_in[1];
  const float* conv1_w = (const float*)d_in[2];
  const float* bn1_g   = (const float*)d_in[3];
  const float* bn1_b   = (const float*)d_in[4];
  const float* M2      = (const float*)d_in[5];
  const float* w0      = (const float*)d_in[6];
  const float* g0      = (const float*)d_in[7];
  const float* b0      = (const float*)d_in[8];
  const float* w1      = (const float*)d_in[9];
  const float* g1      = (const float*)d_in[10];
  const float* b1      = (const float*)d_in[11];
  const float* w2      = (const float*)d_in[12];
  const float* g2      = (const float*)d_in[13];
  const float* b2      = (const float*)d_in[14];
  const float* w3      = (const float*)d_in[15];
  const float* bias3   = (const float*)d_in[16];
  const float* bn2_g   = (const float*)d_in[17];
  const float* bn2_b   = (const float*)d_in[18];
  const int*   idx     = (const int*)d_in[19];
  float* out = (float*)d_out;

  // workspace layout (bytes):  (identical to R11/R14, best measured 312 us)
  //   h      @ 0          (4 MB)
  //   y16    @ 4194304    (16.78 MB, bf16 [B*N][512])
  //   scores @ 20971520   (16.78 MB, fp32 [NPTS][8])
  //   z2p    @ 37748736   (33.55 MB; aliased as Mpart[2048][3840] before k_s2)
  //   z3     @ 71303168   (16.78 MB, bf16 [NPTS][16])
  //   out0   @ 88080384   (4 MB)
  //   sums   @ 92274688   zero 6752 f (stats 352 + M 3840) | affines | frags
  char* wsb = (char*)d_ws;
  float* h      = (float*)wsb;
  u16*   y16    = (u16*)(wsb + 4194304);
  float* scores = (float*)(wsb + 20971520);
  u32*   z2p    = (u32*)(wsb + 37748736);
  u32*   z3     = (u32*)(wsb + 71303168);
  float* out0   = (float*)(wsb + 88080384);
  float* sums   = (float*)(wsb + 92274688);
  float* S_h = sums;        float* Q_h = sums + 64;
  float* S_2 = sums + 128;  float* Q_2 = sums + 160;
  float* S_3 = sums + 192;  float* Q_3 = sums + 208;
  float* S_o = sums + 224;  float* Q_o = sums + 288;
  float* Mm  = sums + 352;                 // 15*256 = 3840 floats (tile-major)
  float* A_h = sums + 6752; float* B_h = sums + 6816;
  float* A_1 = sums + 6880; float* B_1 = sums + 6944;
  float* A_2 = sums + 7008; float* B_2 = sums + 7040;
  float* A_3 = sums + 7072; float* B_3 = sums + 7088;
  float* A_o = sums + 7104; float* B_o = sums + 7168;
  u16* w0frag = (u16*)(sums + 7232);       // 6144 u16
  u16* w1frag = w0frag + 6144;             // 2048 u16
  u16* m2frag = w1frag + 2048;             // 32768 u16 (64 KB)
  float* Mpart = (float*)z2p;              // alias: dead until k_s2

  hipMemsetAsync(sums, 0, 6752 * sizeof(float), stream);

  k_prepM2<<<128, 256, 0, stream>>>(M2, m2frag);
  k_conv1<<<256, 256, 0, stream>>>(x, conv1_w, h, S_h, Q_h);
  k_affine<<<1, 64, 0, stream>>>(S_h, Q_h, bn1_g, bn1_b, A_h, B_h, 64, 1.f / 16384.f);
  k_y<<<256, 256, 0, stream>>>(h, m2frag, A_h, B_h, y16);

  k_moment<<<512, 256, 0, stream>>>(xyz, Mpart);
  k_mreduce<<<dim3(15, 8), 256, 0, stream>>>(Mpart, Mm);
  k_affine1m<<<1, 256, 0, stream>>>(Mm, w0, g0, b0, A_1, B_1);
  k_prep<<<1, 256, 0, stream>>>(w0, w1, A_1, B_1, w0frag, w1frag);
  k_s2<<<2048, 256, 0, stream>>>(xyz, w0frag, w1frag, z2p, S_2, Q_2);
  k_affine<<<1, 64, 0, stream>>>(S_2, Q_2, g1, b1, A_2, B_2, 32, 1.f / (float)NPTS);
  k_s3<<<2048, 256, 0, stream>>>(z2p, w2, A_2, B_2, z3, S_3, Q_3);
  k_affine<<<1, 64, 0, stream>>>(S_3, Q_3, g2, b2, A_3, B_3, 16, 1.f / (float)NPTS);

  k_score<<<2048, 256, 0, stream>>>(z3, w3, bias3, A_3, B_3, scores);
  k_gather<<<2048, 256, 0, stream>>>(y16, scores, idx, out0, S_o, Q_o);
  k_affine<<<1, 64, 0, stream>>>(S_o, Q_o, bn2_g, bn2_b, A_o, B_o, 64, 1.f / 16384.f);
  k_bn2<<<1024, 256, 0, stream>>>(out0, A_o, B_o, out);
}